// Round 5
// baseline (393.171 us; speedup 1.0000x reference)
//
#include <hip/hip_runtime.h>
#include <math.h>

// Problem constants (from reference setup_inputs)
#define B_BATCH 2
#define T_SEQ   2048
#define E_DIM   1024
#define H_HEADS 16
#define D_HEAD  64
#define F_DIM   4096
#define M_ROWS  (B_BATCH * T_SEQ)   // 4096

typedef __attribute__((ext_vector_type(8))) short short8;       // bf16x8 MFMA frag
typedef __attribute__((ext_vector_type(4))) float floatx4;      // MFMA acc
typedef __attribute__((ext_vector_type(8))) unsigned short ushortx8;

typedef __attribute__((address_space(1))) const void global_cvoid;
typedef __attribute__((address_space(3))) void lds_void;

__device__ __forceinline__ unsigned short f2bf(float f) {      // RNE f32->bf16
    unsigned u = __float_as_uint(f);
    u += 0x7fffu + ((u >> 16) & 1u);
    return (unsigned short)(u >> 16);
}
__device__ __forceinline__ float bf2f(unsigned short h) {
    return __uint_as_float(((unsigned)h) << 16);
}

__device__ __forceinline__ float waveReduceSum(float v) {
#pragma unroll
    for (int off = 32; off > 0; off >>= 1) v += __shfl_xor(v, off, 64);
    return v;
}

// ---------------- fp32 -> bf16 convert (weights), n % 1024 == 0 ------------
__global__ __launch_bounds__(256) void cvt_kernel(const float* __restrict__ in,
                                                  unsigned short* __restrict__ out,
                                                  int n) {
    const int i = (blockIdx.x * 256 + threadIdx.x) * 4;
    if (i >= n) return;
    float4 v = *(const float4*)(in + i);
    ushort4 o;
    o.x = f2bf(v.x); o.y = f2bf(v.y); o.z = f2bf(v.z); o.w = f2bf(v.w);
    *(ushort4*)(out + i) = o;
}

// ---------------- fp32 copy (seed for split-K atomics) ----------------------
__global__ __launch_bounds__(256) void copy_kernel(const float* __restrict__ in,
                                                   float* __restrict__ out, int n) {
    const int i = (blockIdx.x * 256 + threadIdx.x) * 4;
    if (i >= n) return;
    *(float4*)(out + i) = *(const float4*)(in + i);
}

// ---------------- RoPE cos/sin table: tab[pos*32+i] = {cos, sin} -----------
__global__ __launch_bounds__(256) void rope_tab_kernel(float* __restrict__ tab) {
    const int idx = blockIdx.x * 256 + threadIdx.x;   // 0 .. T*32-1
    const int pos = idx >> 5, i = idx & 31;
    const float invf = powf(10000.0f, -(float)i / 32.0f);
    const float ang = (float)pos * invf;
    tab[idx * 2]     = cosf(ang);
    tab[idx * 2 + 1] = sinf(ang);
}

// ---------------- LayerNorm: fp32 in, bf16 out ------------------------------
__global__ __launch_bounds__(256) void ln_kernel(const float* __restrict__ x,
                                                 const float* __restrict__ g,
                                                 const float* __restrict__ b,
                                                 unsigned short* __restrict__ out) {
    const int row = blockIdx.x;
    const float* xr = x + (size_t)row * E_DIM;
    float4 v = ((const float4*)xr)[threadIdx.x];
    float s  = v.x + v.y + v.z + v.w;
    float sq = v.x * v.x + v.y * v.y + v.z * v.z + v.w * v.w;

    __shared__ float red[8];
    float ws_ = waveReduceSum(s);
    float wq  = waveReduceSum(sq);
    int wid = threadIdx.x >> 6;
    if ((threadIdx.x & 63) == 0) { red[wid] = ws_; red[wid + 4] = wq; }
    __syncthreads();
    float ts = red[0] + red[1] + red[2] + red[3];
    float tq = red[4] + red[5] + red[6] + red[7];
    float mean = ts * (1.0f / E_DIM);
    float var  = tq * (1.0f / E_DIM) - mean * mean;
    float inv  = rsqrtf(var + 1e-5f);

    float4 gv = ((const float4*)g)[threadIdx.x];
    float4 bv = ((const float4*)b)[threadIdx.x];
    ushort4 o;
    o.x = f2bf((v.x - mean) * inv * gv.x + bv.x);
    o.y = f2bf((v.y - mean) * inv * gv.y + bv.y);
    o.z = f2bf((v.z - mean) * inv * gv.z + bv.z);
    o.w = f2bf((v.w - mean) * inv * gv.w + bv.w);
    ((ushort4*)(out + (size_t)row * E_DIM))[threadIdx.x] = o;
}

// ---------------- bf16 MFMA GEMM: C[M,N] = A[M,K] @ W[N,K]^T ----------------
// blockIdx.z = K-split chunk (gridDim.z chunks); EPI=5 for split-K atomics.
// EPI: 0 = fp32 store, 1 = fp32 store acc+R, 2 = bf16 store gelu(acc),
//      3 = fp32 C += acc, 4 = bf16 store, 5 = fp32 atomicAdd
template <int EPI>
__global__ __launch_bounds__(256) void gemm_bf16(const unsigned short* __restrict__ A,
                                                 const unsigned short* __restrict__ Wt,
                                                 const float* __restrict__ R,
                                                 float* __restrict__ Cf,
                                                 unsigned short* __restrict__ Cb,
                                                 int M, int N, int K) {
    __shared__ unsigned short As[128 * 64];
    __shared__ unsigned short Bs[128 * 64];
    const int tid  = threadIdx.x;
    const int wave = tid >> 6, lane = tid & 63;
    const int wm   = wave >> 1, wn = wave & 1;
    const int quad = lane >> 4, l16 = lane & 15;
    const int m0 = blockIdx.y * 128, n0 = blockIdx.x * 128;
    const int Kc   = K / gridDim.z;
    const int kbeg = blockIdx.z * Kc;

    const int row_rel = lane >> 3;   // 0..7: row within 8-row DMA chunk
    const int ch      = lane & 7;    // phys 16B chunk within row

    const floatx4 z = {0.0f, 0.0f, 0.0f, 0.0f};
    floatx4 acc[4][4];
#pragma unroll
    for (int i = 0; i < 4; ++i)
#pragma unroll
        for (int j = 0; j < 4; ++j) acc[i][j] = z;

    for (int k0 = kbeg; k0 < kbeg + Kc; k0 += 64) {
        __syncthreads();
#pragma unroll
        for (int i = 0; i < 4; ++i) {
            const int chunk = wave * 4 + i;          // 0..15 (8 rows each)
            const int grow  = chunk * 8 + row_rel;   // tile row 0..127
            const int lch   = ch ^ (grow & 7);       // swizzled source chunk
            const unsigned short* ga = A  + (size_t)(m0 + grow) * K + k0 + lch * 8;
            const unsigned short* gb = Wt + (size_t)(n0 + grow) * K + k0 + lch * 8;
            __builtin_amdgcn_global_load_lds((global_cvoid*)ga,
                                             (lds_void*)(As + chunk * 512), 16, 0, 0);
            __builtin_amdgcn_global_load_lds((global_cvoid*)gb,
                                             (lds_void*)(Bs + chunk * 512), 16, 0, 0);
        }
        __syncthreads();

#pragma unroll
        for (int ks = 0; ks < 2; ++ks) {
            short8 af[4], bfr[4];
#pragma unroll
            for (int mt = 0; mt < 4; ++mt) {
                const int r = wm * 64 + mt * 16 + l16;
                const int p = (ks * 4 + quad) ^ (r & 7);
                af[mt] = *(const short8*)(As + r * 64 + p * 8);
            }
#pragma unroll
            for (int nt = 0; nt < 4; ++nt) {
                const int r = wn * 64 + nt * 16 + l16;
                const int p = (ks * 4 + quad) ^ (r & 7);
                bfr[nt] = *(const short8*)(Bs + r * 64 + p * 8);
            }
#pragma unroll
            for (int mt = 0; mt < 4; ++mt)
#pragma unroll
                for (int nt = 0; nt < 4; ++nt)
                    acc[mt][nt] = __builtin_amdgcn_mfma_f32_16x16x32_bf16(
                        af[mt], bfr[nt], acc[mt][nt], 0, 0, 0);
        }
    }

    // Epilogue. C/D layout: col = lane&15, row = quad*4 + reg  [m89-verified]
#pragma unroll
    for (int mt = 0; mt < 4; ++mt) {
        const int rb = m0 + wm * 64 + mt * 16 + quad * 4;
#pragma unroll
        for (int nt = 0; nt < 4; ++nt) {
            const int col = n0 + wn * 64 + nt * 16 + l16;
#pragma unroll
            for (int r = 0; r < 4; ++r) {
                const size_t idx = (size_t)(rb + r) * N + col;
                const float v = acc[mt][nt][r];
                if (EPI == 0) {
                    Cf[idx] = v;
                } else if (EPI == 1) {
                    Cf[idx] = v + R[idx];
                } else if (EPI == 2) {
                    Cb[idx] = f2bf(0.5f * v * (1.0f + erff(v * 0.70710678118654752f)));
                } else if (EPI == 3) {
                    Cf[idx] += v;
                } else if (EPI == 4) {
                    Cb[idx] = f2bf(v);
                } else {
                    atomicAdd(&Cf[idx], v);
                }
            }
        }
    }
}

// ---------------- V transpose: proj v-part -> vt[(bh*64+d)][T] bf16 --------
__global__ __launch_bounds__(256) void vtrans_kernel(const unsigned short* __restrict__ proj,
                                                     unsigned short* __restrict__ vt) {
    __shared__ unsigned short L[64 * 72];
    const int bh = blockIdx.y, b = bh >> 4, h = bh & 15;
    const int st = blockIdx.x * 64;
    const int tid = threadIdx.x;
    {
        const int srel = tid >> 2, d16 = (tid & 3) * 16;
        const unsigned short* src =
            proj + (size_t)(b * T_SEQ + st + srel) * (3 * E_DIM) + 2 * E_DIM + h * 64 + d16;
        *(short8*)(L + srel * 72 + d16)     = *(const short8*)(src);
        *(short8*)(L + srel * 72 + d16 + 8) = *(const short8*)(src + 8);
    }
    __syncthreads();
    {
        const int d = tid >> 2, s16 = (tid & 3) * 16;
        short8 o0, o1;
#pragma unroll
        for (int j = 0; j < 8; ++j) {
            o0[j] = (short)L[(s16 + j) * 72 + d];
            o1[j] = (short)L[(s16 + 8 + j) * 72 + d];
        }
        unsigned short* dst = vt + (size_t)(bh * 64 + d) * T_SEQ + st + s16;
        *(short8*)dst       = o0;
        *(short8*)(dst + 8) = o1;
    }
}

// ---------------- Flash attention w/ fused RoPE, MFMA -----------------------
__device__ __forceinline__ void rope16(ushortx8 x0, ushortx8 x1, const float* tp,
                                       short8& y0, short8& y1) {
#pragma unroll
    for (int j = 0; j < 4; ++j) {
        const float c = tp[2 * j], s = tp[2 * j + 1];
        const float xr = bf2f(x0[2 * j]), xi = bf2f(x0[2 * j + 1]);
        y0[2 * j]     = (short)f2bf(xr * c - xi * s);
        y0[2 * j + 1] = (short)f2bf(xr * s + xi * c);
    }
#pragma unroll
    for (int j = 0; j < 4; ++j) {
        const float c = tp[8 + 2 * j], s = tp[8 + 2 * j + 1];
        const float xr = bf2f(x1[2 * j]), xi = bf2f(x1[2 * j + 1]);
        y1[2 * j]     = (short)f2bf(xr * c - xi * s);
        y1[2 * j + 1] = (short)f2bf(xr * s + xi * c);
    }
}

__global__ __launch_bounds__(256) void attn_kernel(const unsigned short* __restrict__ proj,
                                                   const unsigned short* __restrict__ vt,
                                                   const float* __restrict__ tab,
                                                   const int* __restrict__ ctxp,
                                                   unsigned short* __restrict__ o) {
    __shared__ unsigned short Qs[64 * 64];
    __shared__ unsigned short Ks[64 * 64];
    __shared__ unsigned short Vs[64 * 64];
    __shared__ unsigned short Ps[4][16 * 64];

    const int ctx = ctxp[0];
    const int tid = threadIdx.x;
    const int wave = tid >> 6, lane = tid & 63;
    const int quad = lane >> 4, l16 = lane & 15;
    const int bh = blockIdx.y, b = bh >> 4, h = bh & 15;
    const int t0 = blockIdx.x * 64;

    // ---- stage Q with RoPE (rows swizzled: chunk c at phys c^(row&7)) ----
    {
        const int r = tid >> 2, d16 = (tid & 3) * 16;
        const int pos = t0 + r;
        const unsigned short* src =
            proj + (size_t)(b * T_SEQ + pos) * (3 * E_DIM) + h * 64 + d16;
        ushortx8 x0 = *(const ushortx8*)src;
        ushortx8 x1 = *(const ushortx8*)(src + 8);
        const float* tp = tab + ((size_t)pos * 32 + (d16 >> 1)) * 2;
        short8 y0, y1;
        rope16(x0, x1, tp, y0, y1);
        const int c0 = (tid & 3) * 2;
        *(short8*)(Qs + r * 64 + ((c0)     ^ (r & 7)) * 8) = y0;
        *(short8*)(Qs + r * 64 + ((c0 + 1) ^ (r & 7)) * 8) = y1;
    }

    int first = t0 - (ctx - 1);
    if (first < 0) first = 0;
    const int first_base = first & ~63;

    float m[4] = {-1e30f, -1e30f, -1e30f, -1e30f};
    float l[4] = {0.0f, 0.0f, 0.0f, 0.0f};
    const floatx4 z = {0.0f, 0.0f, 0.0f, 0.0f};
    floatx4 accO[4] = {z, z, z, z};

    const int q_row0 = t0 + wave * 16 + quad * 4;   // abs query of reg r=0

    for (int s_base = first_base; s_base <= t0; s_base += 64) {
        __syncthreads();
        // ---- stage K with RoPE ----
        {
            const int r = tid >> 2, d16 = (tid & 3) * 16;
            const int pos = s_base + r;
            const unsigned short* src =
                proj + (size_t)(b * T_SEQ + pos) * (3 * E_DIM) + E_DIM + h * 64 + d16;
            ushortx8 x0 = *(const ushortx8*)src;
            ushortx8 x1 = *(const ushortx8*)(src + 8);
            const float* tp = tab + ((size_t)pos * 32 + (d16 >> 1)) * 2;
            short8 y0, y1;
            rope16(x0, x1, tp, y0, y1);
            const int c0 = (tid & 3) * 2;
            *(short8*)(Ks + r * 64 + ((c0)     ^ (r & 7)) * 8) = y0;
            *(short8*)(Ks + r * 64 + ((c0 + 1) ^ (r & 7)) * 8) = y1;
        }
        // ---- stage V^T tile via DMA (row d, cols s_base..+63, swizzled) ----
#pragma unroll
        for (int i = 0; i < 2; ++i) {
            const int chunk = (wave * 2 + i) * 64 + lane;   // 0..511
            const int d = chunk >> 3, c = chunk & 7;
            const unsigned short* gsrc =
                vt + (size_t)(bh * 64 + d) * T_SEQ + s_base + ((c ^ (d & 7)) * 8);
            __builtin_amdgcn_global_load_lds((global_cvoid*)gsrc,
                                             (lds_void*)(Vs + (wave * 2 + i) * 512),
                                             16, 0, 0);
        }
        __syncthreads();

        // ---- S = Q K^T (8 MFMA) ----
        floatx4 accS[4] = {z, z, z, z};
#pragma unroll
        for (int ks = 0; ks < 2; ++ks) {
            const int qrow = wave * 16 + l16;
            short8 aq = *(const short8*)(Qs + qrow * 64 + (((ks * 4 + quad) ^ (qrow & 7)) * 8));
#pragma unroll
            for (int nt = 0; nt < 4; ++nt) {
                const int kro = nt * 16 + l16;
                short8 bk = *(const short8*)(Ks + kro * 64 + (((ks * 4 + quad) ^ (kro & 7)) * 8));
                accS[nt] = __builtin_amdgcn_mfma_f32_16x16x32_bf16(aq, bk, accS[nt], 0, 0, 0);
            }
        }

        // ---- mask + online softmax (per q-row r = quad*4+reg) ----
        float p[4][4];      // [nt][r]
        float alpha[4];
#pragma unroll
        for (int r = 0; r < 4; ++r) {
            const int qa = q_row0 + r;
            float sv[4];
            float vmax = -1e30f;
#pragma unroll
            for (int nt = 0; nt < 4; ++nt) {
                const int sa = s_base + nt * 16 + l16;
                const int dd = qa - sa;
                const bool ok = (unsigned)dd < (unsigned)ctx;
                const float s = ok ? accS[nt][r] * 0.125f : -1e30f;
                sv[nt] = s;
                vmax = fmaxf(vmax, s);
            }
            vmax = fmaxf(vmax, __shfl_xor(vmax, 1));
            vmax = fmaxf(vmax, __shfl_xor(vmax, 2));
            vmax = fmaxf(vmax, __shfl_xor(vmax, 4));
            vmax = fmaxf(vmax, __shfl_xor(vmax, 8));
            const float mn = fmaxf(m[r], vmax);
            alpha[r] = __expf(m[r] - mn);
            float ps = 0.0f;
#pragma unroll
            for (int nt = 0; nt < 4; ++nt) {
                const float pe = (sv[nt] > -0.5e30f) ? __expf(sv[nt] - mn) : 0.0f;
                p[nt][r] = pe;
                ps += pe;
            }
            ps += __shfl_xor(ps, 1);
            ps += __shfl_xor(ps, 2);
            ps += __shfl_xor(ps, 4);
            ps += __shfl_xor(ps, 8);
            l[r] = l[r] * alpha[r] + ps;
            m[r] = mn;
        }

        // ---- write P to LDS (C-layout -> A-layout), rescale O ----
#pragma unroll
        for (int nt = 0; nt < 4; ++nt) {
#pragma unroll
            for (int r = 0; r < 4; ++r) {
                const int row = quad * 4 + r;
                const int col = nt * 16 + l16;
                Ps[wave][row * 64 + (((col >> 3) ^ (row & 7)) * 8) + (col & 7)] =
                    f2bf(p[nt][r]);
            }
        }
#pragma unroll
        for (int nt = 0; nt < 4; ++nt)
#pragma unroll
            for (int r = 0; r < 4; ++r) accO[nt][r] *= alpha[r];

        // ---- O += P V (8 MFMA) ----
#pragma unroll
        for (int ks = 0; ks < 2; ++ks) {
            short8 ap = *(const short8*)(&Ps[wave][l16 * 64 + (((ks * 4 + quad) ^ (l16 & 7)) * 8)]);
#pragma unroll
            for (int nt = 0; nt < 4; ++nt) {
                const int dr = nt * 16 + l16;
                short8 bv = *(const short8*)(Vs + dr * 64 + (((ks * 4 + quad) ^ (dr & 7)) * 8));
                accO[nt] = __builtin_amdgcn_mfma_f32_16x16x32_bf16(ap, bv, accO[nt], 0, 0, 0);
            }
        }
    }

    // ---- epilogue: normalize, store bf16 to (B,T,E) ----
    float inv[4];
#pragma unroll
    for (int r = 0; r < 4; ++r) inv[r] = 1.0f / l[r];
#pragma unroll
    for (int nt = 0; nt < 4; ++nt) {
#pragma unroll
        for (int r = 0; r < 4; ++r) {
            const int t = q_row0 + r;
            o[(size_t)(b * T_SEQ + t) * E_DIM + h * 64 + nt * 16 + l16] =
                f2bf(accO[nt][r] * inv[r]);
        }
    }
}

// ---------------------------------------------------------------------------
extern "C" void kernel_launch(void* const* d_in, const int* in_sizes, int n_in,
                              void* d_out, int out_size, void* d_ws, size_t ws_size,
                              hipStream_t stream) {
    const float* x          = (const float*)d_in[0];
    const float* in_proj_w  = (const float*)d_in[1];
    const float* out_proj_w = (const float*)d_in[2];
    const float* ln1_g      = (const float*)d_in[3];
    const float* ln1_b      = (const float*)d_in[4];
    const float* ln2_g      = (const float*)d_in[5];
    const float* ln2_b      = (const float*)d_in[6];
    const float* w1         = (const float*)d_in[7];
    const float* w2         = (const float*)d_in[8];
    const int*   ctx        = (const int*)d_in[9];
    float* out = (float*)d_out;
    float* ws  = (float*)d_ws;

    const size_t MEG = 1024u * 1024u;
    unsigned short* u = (unsigned short*)ws;
    unsigned short* wqkv_b = u;                 // 3M elems
    unsigned short* wout_b = u + 3 * MEG;       // 1M
    unsigned short* w1_b   = u + 4 * MEG;       // 4M
    unsigned short* w2_b   = u + 8 * MEG;       // 4M
    unsigned short* h_b    = u + 12 * MEG;      // 4M (h1, then h2)
    unsigned short* obuf_b = u + 16 * MEG;      // 4M
    unsigned short* proj_b = u + 20 * MEG;      // 12M (B,T,3E bf16)
    unsigned short* vt_b   = u + 32 * MEG;      // 4M  (B*H*64, T) bf16
    unsigned short* mid_b  = u + 36 * MEG;      // 16M (ends at 104 MB)
    float* tab = ws + 26 * MEG;                 // 128K floats (T*32*2) @104MB

    // 0. weights -> bf16; rope table
    cvt_kernel<<<3 * E_DIM * E_DIM / 1024, 256, 0, stream>>>(in_proj_w, wqkv_b, 3 * E_DIM * E_DIM);
    cvt_kernel<<<E_DIM * E_DIM / 1024, 256, 0, stream>>>(out_proj_w, wout_b, E_DIM * E_DIM);
    cvt_kernel<<<F_DIM * E_DIM / 1024, 256, 0, stream>>>(w1, w1_b, F_DIM * E_DIM);
    cvt_kernel<<<E_DIM * F_DIM / 1024, 256, 0, stream>>>(w2, w2_b, E_DIM * F_DIM);
    rope_tab_kernel<<<T_SEQ * 32 / 256, 256, 0, stream>>>(tab);

    // 1. h1 = LN1(x) -> bf16
    ln_kernel<<<M_ROWS, 256, 0, stream>>>(x, ln1_g, ln1_b, h_b);
    // 2. proj = h1 @ in_proj_w^T -> bf16
    gemm_bf16<4><<<dim3(3 * E_DIM / 128, M_ROWS / 128), 256, 0, stream>>>(
        h_b, wqkv_b, nullptr, nullptr, proj_b, M_ROWS, 3 * E_DIM, E_DIM);
    // 3. V^T
    vtrans_kernel<<<dim3(T_SEQ / 64, B_BATCH * H_HEADS), 256, 0, stream>>>(proj_b, vt_b);
    // 4. flash attention (fused RoPE) -> obuf bf16 (B,T,E)
    attn_kernel<<<dim3(T_SEQ / 64, B_BATCH * H_HEADS), 256, 0, stream>>>(
        proj_b, vt_b, tab, ctx, obuf_b);
    // 5. out = x; out += obuf @ out_proj_w^T (split-K=2, atomic)
    copy_kernel<<<M_ROWS * E_DIM / 1024, 256, 0, stream>>>(x, out, M_ROWS * E_DIM);
    gemm_bf16<5><<<dim3(E_DIM / 128, M_ROWS / 128, 2), 256, 0, stream>>>(
        obuf_b, wout_b, nullptr, out, nullptr, M_ROWS, E_DIM, E_DIM);
    // 6. h2 = LN2(out) -> bf16
    ln_kernel<<<M_ROWS, 256, 0, stream>>>(out, ln2_g, ln2_b, h_b);
    // 7. mid = gelu(h2 @ w1^T) -> bf16
    gemm_bf16<2><<<dim3(F_DIM / 128, M_ROWS / 128), 256, 0, stream>>>(
        h_b, w1_b, nullptr, nullptr, mid_b, M_ROWS, F_DIM, E_DIM);
    // 8. out += mid @ w2^T (split-K=4, atomic)
    gemm_bf16<5><<<dim3(E_DIM / 128, M_ROWS / 128, 4), 256, 0, stream>>>(
        mid_b, w2_b, nullptr, out, nullptr, M_ROWS, E_DIM, F_DIM);
}

// Round 6
// 333.237 us; speedup vs baseline: 1.1799x; 1.1799x over previous
//
#include <hip/hip_runtime.h>
#include <math.h>

// Problem constants (from reference setup_inputs)
#define B_BATCH 2
#define T_SEQ   2048
#define E_DIM   1024
#define H_HEADS 16
#define D_HEAD  64
#define F_DIM   4096
#define M_ROWS  (B_BATCH * T_SEQ)   // 4096

typedef __attribute__((ext_vector_type(8))) short short8;       // bf16x8 MFMA frag
typedef __attribute__((ext_vector_type(4))) float floatx4;      // MFMA acc
typedef __attribute__((ext_vector_type(8))) unsigned short ushortx8;

typedef __attribute__((address_space(1))) const void global_cvoid;
typedef __attribute__((address_space(3))) void lds_void;

__device__ __forceinline__ unsigned short f2bf(float f) {      // RNE f32->bf16
    unsigned u = __float_as_uint(f);
    u += 0x7fffu + ((u >> 16) & 1u);
    return (unsigned short)(u >> 16);
}
__device__ __forceinline__ float bf2f(unsigned short h) {
    return __uint_as_float(((unsigned)h) << 16);
}

__device__ __forceinline__ float waveReduceSum(float v) {
#pragma unroll
    for (int off = 32; off > 0; off >>= 1) v += __shfl_xor(v, off, 64);
    return v;
}

// ---------------- fp32 -> bf16 convert (weights), n % 1024 == 0 ------------
__global__ __launch_bounds__(256) void cvt_kernel(const float* __restrict__ in,
                                                  unsigned short* __restrict__ out,
                                                  int n) {
    const int i = (blockIdx.x * 256 + threadIdx.x) * 4;
    if (i >= n) return;
    float4 v = *(const float4*)(in + i);
    ushort4 o;
    o.x = f2bf(v.x); o.y = f2bf(v.y); o.z = f2bf(v.z); o.w = f2bf(v.w);
    *(ushort4*)(out + i) = o;
}

// ---------------- split-K reduce: out += p0 + p1 ----------------------------
__global__ __launch_bounds__(256) void reduce_kernel(const float* __restrict__ p0,
                                                     const float* __restrict__ p1,
                                                     float* __restrict__ out, int n) {
    const int i = (blockIdx.x * 256 + threadIdx.x) * 4;
    if (i >= n) return;
    float4 a = *(const float4*)(out + i);
    float4 b = *(const float4*)(p0 + i);
    float4 c = *(const float4*)(p1 + i);
    a.x += b.x + c.x; a.y += b.y + c.y; a.z += b.z + c.z; a.w += b.w + c.w;
    *(float4*)(out + i) = a;
}

// ---------------- RoPE cos/sin table: tab[pos*32+i] = {cos, sin} -----------
__global__ __launch_bounds__(256) void rope_tab_kernel(float* __restrict__ tab) {
    const int idx = blockIdx.x * 256 + threadIdx.x;   // 0 .. T*32-1
    const int pos = idx >> 5, i = idx & 31;
    const float invf = powf(10000.0f, -(float)i / 32.0f);
    const float ang = (float)pos * invf;
    tab[idx * 2]     = cosf(ang);
    tab[idx * 2 + 1] = sinf(ang);
}

// ---------------- LayerNorm: fp32 in, bf16 out ------------------------------
__global__ __launch_bounds__(256) void ln_kernel(const float* __restrict__ x,
                                                 const float* __restrict__ g,
                                                 const float* __restrict__ b,
                                                 unsigned short* __restrict__ out) {
    const int row = blockIdx.x;
    const float* xr = x + (size_t)row * E_DIM;
    float4 v = ((const float4*)xr)[threadIdx.x];
    float s  = v.x + v.y + v.z + v.w;
    float sq = v.x * v.x + v.y * v.y + v.z * v.z + v.w * v.w;

    __shared__ float red[8];
    float ws_ = waveReduceSum(s);
    float wq  = waveReduceSum(sq);
    int wid = threadIdx.x >> 6;
    if ((threadIdx.x & 63) == 0) { red[wid] = ws_; red[wid + 4] = wq; }
    __syncthreads();
    float ts = red[0] + red[1] + red[2] + red[3];
    float tq = red[4] + red[5] + red[6] + red[7];
    float mean = ts * (1.0f / E_DIM);
    float var  = tq * (1.0f / E_DIM) - mean * mean;
    float inv  = rsqrtf(var + 1e-5f);

    float4 gv = ((const float4*)g)[threadIdx.x];
    float4 bv = ((const float4*)b)[threadIdx.x];
    ushort4 o;
    o.x = f2bf((v.x - mean) * inv * gv.x + bv.x);
    o.y = f2bf((v.y - mean) * inv * gv.y + bv.y);
    o.z = f2bf((v.z - mean) * inv * gv.z + bv.z);
    o.w = f2bf((v.w - mean) * inv * gv.w + bv.w);
    ((ushort4*)(out + (size_t)row * E_DIM))[threadIdx.x] = o;
}

// ---------------- bf16 MFMA GEMM: C[M,N] = A[M,K] @ W[N,K]^T ----------------
// blockIdx.z = K-split chunk (gridDim.z chunks).
// EPI: 0 = fp32 store, 1 = fp32 store acc+R, 2 = bf16 store gelu(acc),
//      3 = fp32 C += acc, 4 = bf16 store, 5 = fp32 partial store (z-sliced)
template <int EPI>
__global__ __launch_bounds__(256) void gemm_bf16(const unsigned short* __restrict__ A,
                                                 const unsigned short* __restrict__ Wt,
                                                 const float* __restrict__ R,
                                                 float* __restrict__ Cf,
                                                 unsigned short* __restrict__ Cb,
                                                 int M, int N, int K) {
    __shared__ unsigned short As[128 * 64];
    __shared__ unsigned short Bs[128 * 64];
    const int tid  = threadIdx.x;
    const int wave = tid >> 6, lane = tid & 63;
    const int wm   = wave >> 1, wn = wave & 1;
    const int quad = lane >> 4, l16 = lane & 15;
    const int m0 = blockIdx.y * 128, n0 = blockIdx.x * 128;
    const int Kc   = K / gridDim.z;
    const int kbeg = blockIdx.z * Kc;

    const int row_rel = lane >> 3;   // 0..7: row within 8-row DMA chunk
    const int ch      = lane & 7;    // phys 16B chunk within row

    const floatx4 z = {0.0f, 0.0f, 0.0f, 0.0f};
    floatx4 acc[4][4];
#pragma unroll
    for (int i = 0; i < 4; ++i)
#pragma unroll
        for (int j = 0; j < 4; ++j) acc[i][j] = z;

    for (int k0 = kbeg; k0 < kbeg + Kc; k0 += 64) {
        __syncthreads();
#pragma unroll
        for (int i = 0; i < 4; ++i) {
            const int chunk = wave * 4 + i;          // 0..15 (8 rows each)
            const int grow  = chunk * 8 + row_rel;   // tile row 0..127
            const int lch   = ch ^ (grow & 7);       // swizzled source chunk
            const unsigned short* ga = A  + (size_t)(m0 + grow) * K + k0 + lch * 8;
            const unsigned short* gb = Wt + (size_t)(n0 + grow) * K + k0 + lch * 8;
            __builtin_amdgcn_global_load_lds((global_cvoid*)ga,
                                             (lds_void*)(As + chunk * 512), 16, 0, 0);
            __builtin_amdgcn_global_load_lds((global_cvoid*)gb,
                                             (lds_void*)(Bs + chunk * 512), 16, 0, 0);
        }
        __syncthreads();

#pragma unroll
        for (int ks = 0; ks < 2; ++ks) {
            short8 af[4], bfr[4];
#pragma unroll
            for (int mt = 0; mt < 4; ++mt) {
                const int r = wm * 64 + mt * 16 + l16;
                const int p = (ks * 4 + quad) ^ (r & 7);
                af[mt] = *(const short8*)(As + r * 64 + p * 8);
            }
#pragma unroll
            for (int nt = 0; nt < 4; ++nt) {
                const int r = wn * 64 + nt * 16 + l16;
                const int p = (ks * 4 + quad) ^ (r & 7);
                bfr[nt] = *(const short8*)(Bs + r * 64 + p * 8);
            }
#pragma unroll
            for (int mt = 0; mt < 4; ++mt)
#pragma unroll
                for (int nt = 0; nt < 4; ++nt)
                    acc[mt][nt] = __builtin_amdgcn_mfma_f32_16x16x32_bf16(
                        af[mt], bfr[nt], acc[mt][nt], 0, 0, 0);
        }
    }

    // Epilogue. C/D layout: col = lane&15, row = quad*4 + reg  [m89-verified]
    const size_t zoff = (size_t)blockIdx.z * M * N;
#pragma unroll
    for (int mt = 0; mt < 4; ++mt) {
        const int rb = m0 + wm * 64 + mt * 16 + quad * 4;
#pragma unroll
        for (int nt = 0; nt < 4; ++nt) {
            const int col = n0 + wn * 64 + nt * 16 + l16;
#pragma unroll
            for (int r = 0; r < 4; ++r) {
                const size_t idx = (size_t)(rb + r) * N + col;
                const float v = acc[mt][nt][r];
                if (EPI == 0) {
                    Cf[idx] = v;
                } else if (EPI == 1) {
                    Cf[idx] = v + R[idx];
                } else if (EPI == 2) {
                    Cb[idx] = f2bf(0.5f * v * (1.0f + erff(v * 0.70710678118654752f)));
                } else if (EPI == 3) {
                    Cf[idx] += v;
                } else if (EPI == 4) {
                    Cb[idx] = f2bf(v);
                } else {
                    Cf[zoff + idx] = v;   // split-K partial, coalesced
                }
            }
        }
    }
}

// ---------------- V transpose: proj v-part -> vt[(bh*64+d)][T] bf16 --------
__global__ __launch_bounds__(256) void vtrans_kernel(const unsigned short* __restrict__ proj,
                                                     unsigned short* __restrict__ vt) {
    __shared__ unsigned short L[64 * 72];
    const int bh = blockIdx.y, b = bh >> 4, h = bh & 15;
    const int st = blockIdx.x * 64;
    const int tid = threadIdx.x;
    {
        const int srel = tid >> 2, d16 = (tid & 3) * 16;
        const unsigned short* src =
            proj + (size_t)(b * T_SEQ + st + srel) * (3 * E_DIM) + 2 * E_DIM + h * 64 + d16;
        *(short8*)(L + srel * 72 + d16)     = *(const short8*)(src);
        *(short8*)(L + srel * 72 + d16 + 8) = *(const short8*)(src + 8);
    }
    __syncthreads();
    {
        const int d = tid >> 2, s16 = (tid & 3) * 16;
        short8 o0, o1;
#pragma unroll
        for (int j = 0; j < 8; ++j) {
            o0[j] = (short)L[(s16 + j) * 72 + d];
            o1[j] = (short)L[(s16 + 8 + j) * 72 + d];
        }
        unsigned short* dst = vt + (size_t)(bh * 64 + d) * T_SEQ + st + s16;
        *(short8*)dst       = o0;
        *(short8*)(dst + 8) = o1;
    }
}

// ---------------- Flash attention w/ fused RoPE, MFMA -----------------------
__device__ __forceinline__ void rope16(ushortx8 x0, ushortx8 x1, const float* tp,
                                       short8& y0, short8& y1) {
#pragma unroll
    for (int j = 0; j < 4; ++j) {
        const float c = tp[2 * j], s = tp[2 * j + 1];
        const float xr = bf2f(x0[2 * j]), xi = bf2f(x0[2 * j + 1]);
        y0[2 * j]     = (short)f2bf(xr * c - xi * s);
        y0[2 * j + 1] = (short)f2bf(xr * s + xi * c);
    }
#pragma unroll
    for (int j = 0; j < 4; ++j) {
        const float c = tp[8 + 2 * j], s = tp[8 + 2 * j + 1];
        const float xr = bf2f(x1[2 * j]), xi = bf2f(x1[2 * j + 1]);
        y1[2 * j]     = (short)f2bf(xr * c - xi * s);
        y1[2 * j + 1] = (short)f2bf(xr * s + xi * c);
    }
}

__global__ __launch_bounds__(256) void attn_kernel(const unsigned short* __restrict__ proj,
                                                   const unsigned short* __restrict__ vt,
                                                   const float* __restrict__ tab,
                                                   const int* __restrict__ ctxp,
                                                   unsigned short* __restrict__ o) {
    __shared__ unsigned short Qs[64 * 64];
    __shared__ unsigned short Ks[64 * 64];
    __shared__ unsigned short Vs[64 * 64];
    __shared__ unsigned short Ps[4][16 * 64];

    const int ctx = ctxp[0];
    const int tid = threadIdx.x;
    const int wave = tid >> 6, lane = tid & 63;
    const int quad = lane >> 4, l16 = lane & 15;
    const int bh = blockIdx.y, b = bh >> 4, h = bh & 15;
    const int t0 = blockIdx.x * 64;

    // ---- stage Q with RoPE (rows swizzled: chunk c at phys c^(row&7)) ----
    {
        const int r = tid >> 2, d16 = (tid & 3) * 16;
        const int pos = t0 + r;
        const unsigned short* src =
            proj + (size_t)(b * T_SEQ + pos) * (3 * E_DIM) + h * 64 + d16;
        ushortx8 x0 = *(const ushortx8*)src;
        ushortx8 x1 = *(const ushortx8*)(src + 8);
        const float* tp = tab + ((size_t)pos * 32 + (d16 >> 1)) * 2;
        short8 y0, y1;
        rope16(x0, x1, tp, y0, y1);
        const int c0 = (tid & 3) * 2;
        *(short8*)(Qs + r * 64 + ((c0)     ^ (r & 7)) * 8) = y0;
        *(short8*)(Qs + r * 64 + ((c0 + 1) ^ (r & 7)) * 8) = y1;
    }

    int first = t0 - (ctx - 1);
    if (first < 0) first = 0;
    const int first_base = first & ~63;

    float m[4] = {-1e30f, -1e30f, -1e30f, -1e30f};
    float l[4] = {0.0f, 0.0f, 0.0f, 0.0f};
    const floatx4 z = {0.0f, 0.0f, 0.0f, 0.0f};
    floatx4 accO[4] = {z, z, z, z};

    const int q_row0 = t0 + wave * 16 + quad * 4;   // abs query of reg r=0

    for (int s_base = first_base; s_base <= t0; s_base += 64) {
        __syncthreads();
        // ---- stage K with RoPE ----
        {
            const int r = tid >> 2, d16 = (tid & 3) * 16;
            const int pos = s_base + r;
            const unsigned short* src =
                proj + (size_t)(b * T_SEQ + pos) * (3 * E_DIM) + E_DIM + h * 64 + d16;
            ushortx8 x0 = *(const ushortx8*)src;
            ushortx8 x1 = *(const ushortx8*)(src + 8);
            const float* tp = tab + ((size_t)pos * 32 + (d16 >> 1)) * 2;
            short8 y0, y1;
            rope16(x0, x1, tp, y0, y1);
            const int c0 = (tid & 3) * 2;
            *(short8*)(Ks + r * 64 + ((c0)     ^ (r & 7)) * 8) = y0;
            *(short8*)(Ks + r * 64 + ((c0 + 1) ^ (r & 7)) * 8) = y1;
        }
        // ---- stage V^T tile via DMA (row d, cols s_base..+63, swizzled) ----
#pragma unroll
        for (int i = 0; i < 2; ++i) {
            const int chunk = (wave * 2 + i) * 64 + lane;   // 0..511
            const int d = chunk >> 3, c = chunk & 7;
            const unsigned short* gsrc =
                vt + (size_t)(bh * 64 + d) * T_SEQ + s_base + ((c ^ (d & 7)) * 8);
            __builtin_amdgcn_global_load_lds((global_cvoid*)gsrc,
                                             (lds_void*)(Vs + (wave * 2 + i) * 512),
                                             16, 0, 0);
        }
        __syncthreads();

        // ---- S = Q K^T (8 MFMA) ----
        floatx4 accS[4] = {z, z, z, z};
#pragma unroll
        for (int ks = 0; ks < 2; ++ks) {
            const int qrow = wave * 16 + l16;
            short8 aq = *(const short8*)(Qs + qrow * 64 + (((ks * 4 + quad) ^ (qrow & 7)) * 8));
#pragma unroll
            for (int nt = 0; nt < 4; ++nt) {
                const int kro = nt * 16 + l16;
                short8 bk = *(const short8*)(Ks + kro * 64 + (((ks * 4 + quad) ^ (kro & 7)) * 8));
                accS[nt] = __builtin_amdgcn_mfma_f32_16x16x32_bf16(aq, bk, accS[nt], 0, 0, 0);
            }
        }

        // ---- mask + online softmax (per q-row r = quad*4+reg) ----
        float p[4][4];      // [nt][r]
        float alpha[4];
#pragma unroll
        for (int r = 0; r < 4; ++r) {
            const int qa = q_row0 + r;
            float sv[4];
            float vmax = -1e30f;
#pragma unroll
            for (int nt = 0; nt < 4; ++nt) {
                const int sa = s_base + nt * 16 + l16;
                const int dd = qa - sa;
                const bool ok = (unsigned)dd < (unsigned)ctx;
                const float s = ok ? accS[nt][r] * 0.125f : -1e30f;
                sv[nt] = s;
                vmax = fmaxf(vmax, s);
            }
            vmax = fmaxf(vmax, __shfl_xor(vmax, 1));
            vmax = fmaxf(vmax, __shfl_xor(vmax, 2));
            vmax = fmaxf(vmax, __shfl_xor(vmax, 4));
            vmax = fmaxf(vmax, __shfl_xor(vmax, 8));
            const float mn = fmaxf(m[r], vmax);
            alpha[r] = __expf(m[r] - mn);
            float ps = 0.0f;
#pragma unroll
            for (int nt = 0; nt < 4; ++nt) {
                const float pe = (sv[nt] > -0.5e30f) ? __expf(sv[nt] - mn) : 0.0f;
                p[nt][r] = pe;
                ps += pe;
            }
            ps += __shfl_xor(ps, 1);
            ps += __shfl_xor(ps, 2);
            ps += __shfl_xor(ps, 4);
            ps += __shfl_xor(ps, 8);
            l[r] = l[r] * alpha[r] + ps;
            m[r] = mn;
        }

        // ---- write P to LDS (C-layout -> A-layout), rescale O ----
#pragma unroll
        for (int nt = 0; nt < 4; ++nt) {
#pragma unroll
            for (int r = 0; r < 4; ++r) {
                const int row = quad * 4 + r;
                const int col = nt * 16 + l16;
                Ps[wave][row * 64 + (((col >> 3) ^ (row & 7)) * 8) + (col & 7)] =
                    f2bf(p[nt][r]);
            }
        }
#pragma unroll
        for (int nt = 0; nt < 4; ++nt)
#pragma unroll
            for (int r = 0; r < 4; ++r) accO[nt][r] *= alpha[r];

        // ---- O += P V (8 MFMA) ----
#pragma unroll
        for (int ks = 0; ks < 2; ++ks) {
            short8 ap = *(const short8*)(&Ps[wave][l16 * 64 + (((ks * 4 + quad) ^ (l16 & 7)) * 8)]);
#pragma unroll
            for (int nt = 0; nt < 4; ++nt) {
                const int dr = nt * 16 + l16;
                short8 bv = *(const short8*)(Vs + dr * 64 + (((ks * 4 + quad) ^ (dr & 7)) * 8));
                accO[nt] = __builtin_amdgcn_mfma_f32_16x16x32_bf16(ap, bv, accO[nt], 0, 0, 0);
            }
        }
    }

    // ---- epilogue: normalize, store bf16 to (B,T,E) ----
    float inv[4];
#pragma unroll
    for (int r = 0; r < 4; ++r) inv[r] = 1.0f / l[r];
#pragma unroll
    for (int nt = 0; nt < 4; ++nt) {
#pragma unroll
        for (int r = 0; r < 4; ++r) {
            const int t = q_row0 + r;
            o[(size_t)(b * T_SEQ + t) * E_DIM + h * 64 + nt * 16 + l16] =
                f2bf(accO[nt][r] * inv[r]);
        }
    }
}

// ---------------------------------------------------------------------------
extern "C" void kernel_launch(void* const* d_in, const int* in_sizes, int n_in,
                              void* d_out, int out_size, void* d_ws, size_t ws_size,
                              hipStream_t stream) {
    const float* x          = (const float*)d_in[0];
    const float* in_proj_w  = (const float*)d_in[1];
    const float* out_proj_w = (const float*)d_in[2];
    const float* ln1_g      = (const float*)d_in[3];
    const float* ln1_b      = (const float*)d_in[4];
    const float* ln2_g      = (const float*)d_in[5];
    const float* ln2_b      = (const float*)d_in[6];
    const float* w1         = (const float*)d_in[7];
    const float* w2         = (const float*)d_in[8];
    const int*   ctx        = (const int*)d_in[9];
    float* out = (float*)d_out;
    float* ws  = (float*)d_ws;

    const size_t MEG = 1024u * 1024u;
    unsigned short* u = (unsigned short*)ws;
    unsigned short* wqkv_b = u;                 // bytes   0..6 MB
    unsigned short* wout_b = u + 3 * MEG;       // bytes   6..8
    unsigned short* w1_b   = u + 4 * MEG;       // bytes   8..16
    unsigned short* w2_b   = u + 8 * MEG;       // bytes  16..24
    unsigned short* h_b    = u + 12 * MEG;      // bytes  24..32 (h1, then h2; dead после MLP1)
    unsigned short* obuf_b = u + 16 * MEG;      // bytes  32..40 (dead after out-proj)
    unsigned short* proj_b = u + 20 * MEG;      // bytes  40..64 (dead after attn)
    unsigned short* vt_b   = u + 32 * MEG;      // bytes  64..72 (dead after attn)
    unsigned short* mid_b  = u + 36 * MEG;      // bytes  72..104 (alive in MLP2)
    float* tab  = ws + 26 * MEG;                // bytes 104..105
    // split-K partials overlay dead h_b/obuf/proj regions (bytes 24..56 MB):
    float* part = ws + 6 * MEG;                 // 2 slices x 16 MB

    // 0. weights -> bf16; rope table
    cvt_kernel<<<3 * E_DIM * E_DIM / 1024, 256, 0, stream>>>(in_proj_w, wqkv_b, 3 * E_DIM * E_DIM);
    cvt_kernel<<<E_DIM * E_DIM / 1024, 256, 0, stream>>>(out_proj_w, wout_b, E_DIM * E_DIM);
    cvt_kernel<<<F_DIM * E_DIM / 1024, 256, 0, stream>>>(w1, w1_b, F_DIM * E_DIM);
    cvt_kernel<<<E_DIM * F_DIM / 1024, 256, 0, stream>>>(w2, w2_b, E_DIM * F_DIM);
    rope_tab_kernel<<<T_SEQ * 32 / 256, 256, 0, stream>>>(tab);

    // 1. h1 = LN1(x) -> bf16
    ln_kernel<<<M_ROWS, 256, 0, stream>>>(x, ln1_g, ln1_b, h_b);
    // 2. proj = h1 @ in_proj_w^T -> bf16
    gemm_bf16<4><<<dim3(3 * E_DIM / 128, M_ROWS / 128), 256, 0, stream>>>(
        h_b, wqkv_b, nullptr, nullptr, proj_b, M_ROWS, 3 * E_DIM, E_DIM);
    // 3. V^T
    vtrans_kernel<<<dim3(T_SEQ / 64, B_BATCH * H_HEADS), 256, 0, stream>>>(proj_b, vt_b);
    // 4. flash attention (fused RoPE) -> obuf bf16 (B,T,E)
    attn_kernel<<<dim3(T_SEQ / 64, B_BATCH * H_HEADS), 256, 0, stream>>>(
        proj_b, vt_b, tab, ctx, obuf_b);
    // 5. out = x + obuf @ out_proj_w^T (fused residual store)
    gemm_bf16<1><<<dim3(E_DIM / 128, M_ROWS / 128), 256, 0, stream>>>(
        obuf_b, wout_b, x, out, nullptr, M_ROWS, E_DIM, E_DIM);
    // 6. h2 = LN2(out) -> bf16
    ln_kernel<<<M_ROWS, 256, 0, stream>>>(out, ln2_g, ln2_b, h_b);
    // 7. mid = gelu(h2 @ w1^T) -> bf16
    gemm_bf16<2><<<dim3(F_DIM / 128, M_ROWS / 128), 256, 0, stream>>>(
        h_b, w1_b, nullptr, nullptr, mid_b, M_ROWS, F_DIM, E_DIM);
    // 8. part[z] = mid @ w2^T (split-K=2 partials), then out += part0 + part1
    gemm_bf16<5><<<dim3(E_DIM / 128, M_ROWS / 128, 2), 256, 0, stream>>>(
        mid_b, w2_b, nullptr, part, nullptr, M_ROWS, E_DIM, F_DIM);
    reduce_kernel<<<M_ROWS * E_DIM / 1024, 256, 0, stream>>>(
        part, part + (size_t)M_ROWS * E_DIM, out, M_ROWS * E_DIM);
}